// Round 1
// baseline (431.630 us; speedup 1.0000x reference)
//
#include <hip/hip_runtime.h>
#include <math.h>

#define B_ 8
#define L_ 4096
#define H_ 32
#define D_ 128
#define HID_ 4096
#define INTER_ 11008
#define EPS_ 1e-6f

__device__ __forceinline__ float dot4(float4 a, float4 b) {
  return a.x * b.x + a.y * b.y + a.z * b.z + a.w * b.w;
}

__device__ __forceinline__ float wave_sum(float v) {
#pragma unroll
  for (int m = 32; m >= 1; m >>= 1) v += __shfl_xor(v, m, 64);
  return v;
}

// ---------------- RMSNorm: grid=B, block=1024, one float4 per thread ----------------
__global__ __launch_bounds__(1024) void rmsnorm_kernel(const float* __restrict__ x,
                                                       const float* __restrict__ w,
                                                       float* __restrict__ out) {
  int b = blockIdx.x;
  const float4* xb = (const float4*)(x + (size_t)b * HID_);
  const float4* wp = (const float4*)w;
  float4* ob = (float4*)(out + (size_t)b * HID_);
  int tid = threadIdx.x;
  float4 v = xb[tid];
  float ss = v.x * v.x + v.y * v.y + v.z * v.z + v.w * v.w;
  ss = wave_sum(ss);
  __shared__ float red[16];
  int wid = tid >> 6, lane = tid & 63;
  if (lane == 0) red[wid] = ss;
  __syncthreads();
  float tot = 0.f;
#pragma unroll
  for (int i = 0; i < 16; i++) tot += red[i];
  float rs = rsqrtf(tot * (1.0f / (float)HID_) + EPS_);
  float4 wv = wp[tid];
  float4 o;
  o.x = v.x * rs * wv.x;
  o.y = v.y * rs * wv.y;
  o.z = v.z * rs * wv.z;
  o.w = v.w * rs * wv.w;
  ob[tid] = o;
}

// ---------------- GEMV: out[b][n] = dot(x[b], W[n]) (+ res). 2 rows/wave, 8 batches. ----------------
template <int KD>
__global__ __launch_bounds__(256) void gemv_kernel(const float* __restrict__ W,
                                                   const float* __restrict__ x,
                                                   const float* __restrict__ res,
                                                   float* __restrict__ out,
                                                   int ostride) {
  constexpr int NF4 = KD / 4;
  int wave = ((int)blockIdx.x * 256 + (int)threadIdx.x) >> 6;
  int lane = threadIdx.x & 63;
  int n0 = wave * 2;
  const float4* w0 = (const float4*)(W + (size_t)n0 * KD);
  const float4* w1 = w0 + NF4;
  const float4* xp = (const float4*)x;
  float acc0[8] = {0.f, 0.f, 0.f, 0.f, 0.f, 0.f, 0.f, 0.f};
  float acc1[8] = {0.f, 0.f, 0.f, 0.f, 0.f, 0.f, 0.f, 0.f};
#pragma unroll 2
  for (int k4 = lane; k4 < NF4; k4 += 64) {
    float4 a0 = w0[k4];
    float4 a1 = w1[k4];
#pragma unroll
    for (int b = 0; b < 8; b++) {
      float4 xv = xp[b * NF4 + k4];
      acc0[b] += dot4(a0, xv);
      acc1[b] += dot4(a1, xv);
    }
  }
#pragma unroll
  for (int b = 0; b < 8; b++) {
    float v0 = wave_sum(acc0[b]);
    float v1 = wave_sum(acc1[b]);
    if (lane == 0) {
      size_t o = (size_t)b * ostride + n0;
      float r0 = res ? res[o] : 0.f;
      float r1 = res ? res[o + 1] : 0.f;
      out[o] = v0 + r0;
      out[o + 1] = v1 + r1;
    }
  }
}

// ---------------- fused gate/up GEMV + SiLU: act[b][n] = silu(x·gW[n]) * (x·uW[n]) ----------------
__global__ __launch_bounds__(256) void gateup_kernel(const float* __restrict__ gW,
                                                     const float* __restrict__ uW,
                                                     const float* __restrict__ x,
                                                     float* __restrict__ act) {
  constexpr int NF4 = HID_ / 4;
  int wave = ((int)blockIdx.x * 256 + (int)threadIdx.x) >> 6;
  int lane = threadIdx.x & 63;
  int n0 = wave * 2;
  const float4* g0 = (const float4*)(gW + (size_t)n0 * HID_);
  const float4* g1 = g0 + NF4;
  const float4* u0 = (const float4*)(uW + (size_t)n0 * HID_);
  const float4* u1 = u0 + NF4;
  const float4* xp = (const float4*)x;
  float ag0[8] = {0.f, 0.f, 0.f, 0.f, 0.f, 0.f, 0.f, 0.f};
  float ag1[8] = {0.f, 0.f, 0.f, 0.f, 0.f, 0.f, 0.f, 0.f};
  float au0[8] = {0.f, 0.f, 0.f, 0.f, 0.f, 0.f, 0.f, 0.f};
  float au1[8] = {0.f, 0.f, 0.f, 0.f, 0.f, 0.f, 0.f, 0.f};
#pragma unroll 2
  for (int k4 = lane; k4 < NF4; k4 += 64) {
    float4 a0 = g0[k4], a1 = g1[k4], b0 = u0[k4], b1 = u1[k4];
#pragma unroll
    for (int b = 0; b < 8; b++) {
      float4 xv = xp[b * NF4 + k4];
      ag0[b] += dot4(a0, xv);
      ag1[b] += dot4(a1, xv);
      au0[b] += dot4(b0, xv);
      au1[b] += dot4(b1, xv);
    }
  }
#pragma unroll
  for (int b = 0; b < 8; b++) {
    float g0v = wave_sum(ag0[b]);
    float g1v = wave_sum(ag1[b]);
    float u0v = wave_sum(au0[b]);
    float u1v = wave_sum(au1[b]);
    if (lane == 0) {
      size_t o = (size_t)b * INTER_ + n0;
      act[o] = g0v / (1.f + __expf(-g0v)) * u0v;
      act[o + 1] = g1v / (1.f + __expf(-g1v)) * u1v;
    }
  }
}

// ---------------- fused RoPE + attention: one block per (b,h), 16 waves ----------------
__global__ __launch_bounds__(1024) void attn_kernel(const float* __restrict__ qkv,
                                                    const float* __restrict__ kc,
                                                    const float* __restrict__ vc,
                                                    const int* __restrict__ pos,
                                                    float* __restrict__ ctx) {
  int b = blockIdx.x >> 5;
  int h = blockIdx.x & 31;
  int tid = threadIdx.x;
  int wid = tid >> 6, lane = tid & 63;
  int grp = lane >> 3, j = lane & 7;

  __shared__ float s_scores[L_ + 1];
  __shared__ __align__(16) float s_q[D_];
  __shared__ __align__(16) float s_k[D_];
  __shared__ __align__(16) float s_v[D_];
  __shared__ float4 s_part[16][32];
  __shared__ float s_red[16];

  const float* qraw = qkv + (size_t)b * (3 * HID_) + h * D_;
  const float* kraw = qraw + HID_;
  const float* vraw = qraw + 2 * HID_;

  if (tid < 64) {
    float p = (float)pos[b];
    float invf = expf(-((float)tid * (1.0f / 64.0f)) * 9.210340371976184f);
    float ang = p * invf;
    float c = cosf(ang), s = sinf(ang);
    float q1 = qraw[tid], q2 = qraw[tid + 64];
    s_q[tid] = q1 * c - q2 * s;
    s_q[tid + 64] = q1 * s + q2 * c;
    float k1 = kraw[tid], k2 = kraw[tid + 64];
    s_k[tid] = k1 * c - k2 * s;
    s_k[tid + 64] = k1 * s + k2 * c;
  } else if (tid < 192) {
    int d = tid - 64;
    s_v[d] = vraw[d];
  }
  __syncthreads();

  // each lane holds q float4s at f4-index c*8+j  (dims (c*8+j)*4 .. +3)
  float4 qf[4];
#pragma unroll
  for (int c = 0; c < 4; c++) qf[c] = ((const float4*)s_q)[c * 8 + j];

  const float scale = 0.08838834764831845f;  // 1/sqrt(128)

  // score for the new token (lanes 0..7 of wave 0)
  if (tid < 8) {
    float acc = 0.f;
#pragma unroll
    for (int c = 0; c < 4; c++) acc += dot4(((const float4*)s_k)[c * 8 + tid], qf[c]);
    acc += __shfl_xor(acc, 1, 64);
    acc += __shfl_xor(acc, 2, 64);
    acc += __shfl_xor(acc, 4, 64);
    if (tid == 0) s_scores[L_] = acc * scale;
  }

  // ---- scores over the cache: wave wid handles l in [wid*256, wid*256+256), 8 l's per iter ----
  const float* kbase = kc + ((size_t)b * L_ * H_ + h) * D_;
  int l_start = wid * (L_ / 16);
#pragma unroll 2
  for (int l0 = 0; l0 < L_ / 16; l0 += 8) {
    int l = l_start + l0 + grp;
    const float4* kp = (const float4*)(kbase + (size_t)l * (H_ * D_));
    float acc = 0.f;
#pragma unroll
    for (int c = 0; c < 4; c++) acc += dot4(kp[c * 8 + j], qf[c]);
    acc += __shfl_xor(acc, 1, 64);
    acc += __shfl_xor(acc, 2, 64);
    acc += __shfl_xor(acc, 4, 64);
    if (j == 0) s_scores[l] = acc * scale;
  }
  __syncthreads();

  // ---- softmax over L_+1 scores ----
  float mx = -1e30f;
  for (int i = tid; i < L_ + 1; i += 1024) mx = fmaxf(mx, s_scores[i]);
#pragma unroll
  for (int m = 32; m >= 1; m >>= 1) mx = fmaxf(mx, __shfl_xor(mx, m, 64));
  if (lane == 0) s_red[wid] = mx;
  __syncthreads();
#pragma unroll
  for (int i = 0; i < 16; i++) mx = fmaxf(mx, s_red[i]);
  __syncthreads();  // s_red reuse
  float lsum = 0.f;
  for (int i = tid; i < L_ + 1; i += 1024) {
    float e = __expf(s_scores[i] - mx);
    s_scores[i] = e;
    lsum += e;
  }
  lsum = wave_sum(lsum);
  if (lane == 0) s_red[wid] = lsum;
  __syncthreads();
  float sum = 0.f;
#pragma unroll
  for (int i = 0; i < 16; i++) sum += s_red[i];

  // ---- PV: weighted V accumulate ----
  const float* vbase = vc + ((size_t)b * L_ * H_ + h) * D_;
  float4 cacc[4];
#pragma unroll
  for (int c = 0; c < 4; c++) cacc[c] = make_float4(0.f, 0.f, 0.f, 0.f);
#pragma unroll 2
  for (int l0 = 0; l0 < L_ / 16; l0 += 8) {
    int l = l_start + l0 + grp;
    float p = s_scores[l];
    const float4* vp = (const float4*)(vbase + (size_t)l * (H_ * D_));
#pragma unroll
    for (int c = 0; c < 4; c++) {
      float4 vf = vp[c * 8 + j];
      cacc[c].x += p * vf.x;
      cacc[c].y += p * vf.y;
      cacc[c].z += p * vf.z;
      cacc[c].w += p * vf.w;
    }
  }
  // reduce across the 8 groups (lanes sharing j)
#pragma unroll
  for (int c = 0; c < 4; c++) {
#pragma unroll
    for (int m = 8; m <= 32; m <<= 1) {
      cacc[c].x += __shfl_xor(cacc[c].x, m, 64);
      cacc[c].y += __shfl_xor(cacc[c].y, m, 64);
      cacc[c].z += __shfl_xor(cacc[c].z, m, 64);
      cacc[c].w += __shfl_xor(cacc[c].w, m, 64);
    }
  }
  if (lane < 8) {
#pragma unroll
    for (int c = 0; c < 4; c++) s_part[wid][c * 8 + lane] = cacc[c];
  }
  __syncthreads();
  // final cross-wave combine + new-token V + normalize
  if (tid < 32) {
    float4 t = s_part[0][tid];
#pragma unroll
    for (int w = 1; w < 16; w++) {
      float4 pw = s_part[w][tid];
      t.x += pw.x;
      t.y += pw.y;
      t.z += pw.z;
      t.w += pw.w;
    }
    float pn = s_scores[L_];
    float4 vn = ((const float4*)s_v)[tid];
    float inv = 1.f / sum;
    t.x = (t.x + pn * vn.x) * inv;
    t.y = (t.y + pn * vn.y) * inv;
    t.z = (t.z + pn * vn.z) * inv;
    t.w = (t.w + pn * vn.w) * inv;
    ((float4*)(ctx + (size_t)b * HID_ + h * D_))[tid] = t;
  }
}

extern "C" void kernel_launch(void* const* d_in, const int* in_sizes, int n_in,
                              void* d_out, int out_size, void* d_ws, size_t ws_size,
                              hipStream_t stream) {
  (void)in_sizes; (void)n_in; (void)out_size; (void)ws_size;
  const float* hidden = (const float*)d_in[0];
  const float* kc     = (const float*)d_in[1];
  const float* vc     = (const float*)d_in[2];
  const float* w_pack = (const float*)d_in[3];
  const float* o_w    = (const float*)d_in[4];
  const float* gate_w = (const float*)d_in[5];
  const float* up_w   = (const float*)d_in[6];
  const float* down_w = (const float*)d_in[7];
  const float* ln1    = (const float*)d_in[8];
  const float* ln2    = (const float*)d_in[9];
  const int*   pos    = (const int*)d_in[10];
  float* out = (float*)d_out;
  float* ws  = (float*)d_ws;

  float* xn  = ws;            // 32768 (B*HID)
  float* qkv = ws + 32768;    // 98304 (B*3*HID)
  float* ctx = ws + 131072;   // 32768
  float* h1  = ws + 163840;   // 32768
  float* h2  = ws + 196608;   // 32768
  float* act = ws + 229376;   // 88064 (B*INTER)

  // 1. RMSNorm(hidden, ln1) -> xn
  rmsnorm_kernel<<<B_, 1024, 0, stream>>>(hidden, ln1, xn);
  // 2. qkv = xn @ w_pack.T   (12288 rows, 2 rows/wave, 4 waves/block -> 1536 blocks)
  gemv_kernel<HID_><<<1536, 256, 0, stream>>>(w_pack, xn, nullptr, qkv, 3 * HID_);
  // 3. fused RoPE + attention -> ctx
  attn_kernel<<<B_ * H_, 1024, 0, stream>>>(qkv, kc, vc, pos, ctx);
  // 4. h1 = hidden + ctx @ o_proj.T  (4096 rows -> 512 blocks)
  gemv_kernel<HID_><<<512, 256, 0, stream>>>(o_w, ctx, hidden, h1, HID_);
  // 5. RMSNorm(h1, ln2) -> h2
  rmsnorm_kernel<<<B_, 1024, 0, stream>>>(h1, ln2, h2);
  // 6. act = silu(h2@gate.T) * (h2@up.T)   (11008 rows -> 1376 blocks)
  gateup_kernel<<<1376, 256, 0, stream>>>(gate_w, up_w, h2, act);
  // 7. out = h1 + act @ down.T  (4096 rows, K=11008 -> 512 blocks)
  gemv_kernel<INTER_><<<512, 256, 0, stream>>>(down_w, act, h1, out, HID_);
}